// Round 6
// baseline (559.377 us; speedup 1.0000x reference)
//
#include <hip/hip_runtime.h>
#include <hip/hip_bf16.h>

typedef __bf16 bf16;
typedef __bf16 bf16x2 __attribute__((ext_vector_type(2)));
typedef __bf16 bf16x4 __attribute__((ext_vector_type(4)));
typedef __bf16 bf16x8 __attribute__((ext_vector_type(8)));
typedef float f32x4 __attribute__((ext_vector_type(4)));

#define DIM 1536
#define NH 12
#define HD 128
#define SEQ 1560
#define KV 9360
#define KVP 9408      // padded to 147*64 so staging never needs clamps
#define SINK 1560
#define NEWBASE 7800  // k_cat rows [7800,9360) are the new tokens
// logits computed in log2 domain: Q pre-scaled by HD^-0.5 * log2(e)
#define QSCALE_L2E (0.08838834764831845f * 1.4426950408889634f)
#define NSPLIT 6
#define CHUNK 1600    // 25 tiles; splits 0..4 = 25 tiles, split 5 = 22 tiles
#define QBLK 128
#define NQT 13        // ceil(1560/128)

__device__ __forceinline__ void gl_lds16(const void* g, void* l) {
  __builtin_amdgcn_global_load_lds(
      (const __attribute__((address_space(1))) unsigned int*)g,
      (__attribute__((address_space(3))) unsigned int*)l, 16, 0, 0);
}

__device__ __forceinline__ f32x4 vmax4(f32x4 a, f32x4 b) {
  f32x4 r;
  r[0] = fmaxf(a[0], b[0]); r[1] = fmaxf(a[1], b[1]);
  r[2] = fmaxf(a[2], b[2]); r[3] = fmaxf(a[3], b[3]);
  return r;
}

// ---------------- cast f32 -> bf16 ----------------
__global__ __launch_bounds__(256) void castk(const float* __restrict__ src,
                                             bf16* __restrict__ dst, int n) {
  int i = (blockIdx.x * 256 + threadIdx.x) * 8;
  if (i < n) {
    float4 a = *(const float4*)(src + i);
    float4 b = *(const float4*)(src + i + 4);
    bf16x8 o;
    o[0] = (bf16)a.x; o[1] = (bf16)a.y; o[2] = (bf16)a.z; o[3] = (bf16)a.w;
    o[4] = (bf16)b.x; o[5] = (bf16)b.y; o[6] = (bf16)b.z; o[7] = (bf16)b.w;
    *(bf16x8*)(dst + i) = o;
  }
}

// ---------------- GEMM: C[M,N] = A[M,K] * B[N,K]^T + bias, f32 out ----------------
struct GemmBatch {
  const bf16* B[3];
  const float* bias[3];
  float* C[3];
};

#define BM 128
#define BN 128
#define BK 32

__global__ __launch_bounds__(256, 2) void gemm_bt(const bf16* __restrict__ A,
                                                  GemmBatch gb, int M) {
  const bf16* Bw = gb.B[blockIdx.z];
  const float* bias = gb.bias[blockIdx.z];
  float* C = gb.C[blockIdx.z];
  int bm = blockIdx.x * BM;
  int bn = blockIdx.y * BN;

  __shared__ bf16 Alds[2][BM][BK];
  __shared__ bf16 Blds[2][BN][BK];

  int t = threadIdx.x;
  int lane = t & 63;
  int wave = t >> 6;
  int wr = wave >> 1, wc = wave & 1;
  int fr = lane & 15;
  int fo = (lane >> 4) * 8;

  f32x4 acc[4][4] = {};

  const int NK = DIM / BK;  // 48
  int colA = (lane & 3) * 8;
  int lrow = lane >> 2;

#define STAGEG(buf, k0)                                                     \
  {                                                                         \
    _Pragma("unroll") for (int p = 0; p < 2; ++p) {                         \
      int rbase = wave * 16 + p * 64;                                       \
      int ga = bm + rbase + lrow;                                           \
      if (ga > M - 1) ga = M - 1;                                           \
      gl_lds16(A + (size_t)ga * DIM + (k0) + colA, &Alds[buf][rbase][0]);   \
      int gbv = bn + rbase + lrow;                                          \
      gl_lds16(Bw + (size_t)gbv * DIM + (k0) + colA, &Blds[buf][rbase][0]); \
    }                                                                       \
  }

  STAGEG(0, 0);
  int cur = 0;
  for (int ks = 0; ks < NK; ++ks) {
    __syncthreads();  // drains vmcnt -> buf[cur] ready
    if (ks + 1 < NK) STAGEG(cur ^ 1, (ks + 1) * BK);
    bf16x8 af[4], bfv[4];
#pragma unroll
    for (int i = 0; i < 4; ++i)
      af[i] = *(const bf16x8*)&Alds[cur][wr * 64 + i * 16 + fr][fo];
#pragma unroll
    for (int j = 0; j < 4; ++j)
      bfv[j] = *(const bf16x8*)&Blds[cur][wc * 64 + j * 16 + fr][fo];
#pragma unroll
    for (int i = 0; i < 4; ++i)
#pragma unroll
      for (int j = 0; j < 4; ++j)
        acc[i][j] = __builtin_amdgcn_mfma_f32_16x16x32_bf16(af[i], bfv[j],
                                                            acc[i][j], 0, 0, 0);
    cur ^= 1;
  }
#undef STAGEG

  int g4 = (lane >> 4) * 4;
#pragma unroll
  for (int i = 0; i < 4; ++i) {
    int mbase = bm + wr * 64 + i * 16 + g4;
#pragma unroll
    for (int j = 0; j < 4; ++j) {
      int col = bn + wc * 64 + j * 16 + fr;
      float bv = bias[col];
#pragma unroll
      for (int r = 0; r < 4; ++r) {
        int m = mbase + r;
        if (m < M) C[(size_t)m * DIM + col] = acc[i][j][r] + bv;
      }
    }
  }
}

// ---------------- RMSNorm + RoPE for q,k ----------------
__global__ __launch_bounds__(256) void norm_rope(
    const float* __restrict__ qraw, const float* __restrict__ kraw,
    const float* __restrict__ nqw, const float* __restrict__ nkw,
    const float* __restrict__ fcos, const float* __restrict__ fsin,
    bf16* __restrict__ Qh, bf16* __restrict__ Kcat) {
  int tok = blockIdx.x;
  int tid = threadIdx.x;
  const float* qr = qraw + (size_t)tok * DIM;
  const float* kr = kraw + (size_t)tok * DIM;
  float sq = 0.f, sk = 0.f;
  for (int c = tid; c < DIM; c += 256) {
    float a = qr[c];
    sq += a * a;
    float b = kr[c];
    sk += b * b;
  }
#pragma unroll
  for (int off = 32; off; off >>= 1) {
    sq += __shfl_down(sq, off);
    sk += __shfl_down(sk, off);
  }
  __shared__ float red[2][4];
  int w = tid >> 6;
  if ((tid & 63) == 0) {
    red[0][w] = sq;
    red[1][w] = sk;
  }
  __syncthreads();
  sq = red[0][0] + red[0][1] + red[0][2] + red[0][3];
  sk = red[1][0] + red[1][1] + red[1][2] + red[1][3];
  float rsq = rsqrtf(sq * (1.0f / DIM) + 1e-6f);
  float rsk = rsqrtf(sk * (1.0f / DIM) + 1e-6f);

  int hrow = tok / 52, wrow = tok % 52;
  for (int p = tid; p < NH * 64; p += 256) {
    int n = p >> 6, i = p & 63;
    int trow = (i < 22) ? 6 : (i < 43 ? hrow : wrow);
    float cs = fcos[trow * 64 + i];
    float sn = fsin[trow * 64 + i];
    int c = n * HD + 2 * i;
    float xr = qr[c] * rsq * nqw[c];
    float xi = qr[c + 1] * rsq * nqw[c + 1];
    bf16x2 qo;
    qo[0] = (bf16)((xr * cs - xi * sn) * QSCALE_L2E);
    qo[1] = (bf16)((xr * sn + xi * cs) * QSCALE_L2E);
    *(bf16x2*)(Qh + ((size_t)n * SEQ + tok) * HD + 2 * i) = qo;
    float yr = kr[c] * rsk * nkw[c];
    float yi = kr[c + 1] * rsk * nkw[c + 1];
    bf16x2 ko;
    ko[0] = (bf16)(yr * cs - yi * sn);
    ko[1] = (bf16)(yr * sn + yi * cs);
    *(bf16x2*)(Kcat + ((size_t)n * KVP + NEWBASE + tok) * HD + 2 * i) = ko;
  }
}

// ---------------- gather cache_k rows into K_cat ----------------
__global__ __launch_bounds__(256) void build_kcat(const float* __restrict__ cache_k,
                                                  bf16* __restrict__ Kcat) {
  int j = blockIdx.x;  // 0..7799
  int src = j < SINK ? j : j + SINK;
  const float* sp = cache_k + (size_t)src * DIM;
  for (int c4 = threadIdx.x; c4 < DIM / 4; c4 += 256) {
    float4 v = *(const float4*)(sp + c4 * 4);
    int c = c4 * 4;
    int n = c >> 7, d = c & 127;
    bf16x4 o;
    o[0] = (bf16)v.x; o[1] = (bf16)v.y; o[2] = (bf16)v.z; o[3] = (bf16)v.w;
    *(bf16x4*)(Kcat + ((size_t)n * KVP + j) * HD + d) = o;
  }
}

// ---------------- build transposed V: Vt[h][d][j] ----------------
__global__ __launch_bounds__(256) void build_vt(const float* __restrict__ cache_v,
                                                const float* __restrict__ vraw,
                                                bf16* __restrict__ Vt) {
  int h = blockIdx.y;
  int j0 = blockIdx.x * 64;
  __shared__ bf16 T[128][72];
  int tid = threadIdx.x;
  for (int idx = tid; idx < 64 * 32; idx += 256) {
    int jl = idx >> 5, s = idx & 31;
    int j = j0 + jl;
    if (j >= KV) continue;
    const float* sp;
    if (j < NEWBASE) {
      int srcj = j < SINK ? j : j + SINK;
      sp = cache_v + (size_t)srcj * DIM + h * HD;
    } else {
      sp = vraw + (size_t)(j - NEWBASE) * DIM + h * HD;
    }
    float4 v = *(const float4*)(sp + s * 4);
    T[s * 4 + 0][jl] = (bf16)v.x;
    T[s * 4 + 1][jl] = (bf16)v.y;
    T[s * 4 + 2][jl] = (bf16)v.z;
    T[s * 4 + 3][jl] = (bf16)v.w;
  }
  __syncthreads();
  for (int idx = tid; idx < 128 * 16; idx += 256) {
    int d = idx >> 4, g = idx & 15;
    int j = j0 + g * 4;
    if (j + 4 > KV) continue;
    bf16x4 o;
    o[0] = T[d][4 * g];
    o[1] = T[d][4 * g + 1];
    o[2] = T[d][4 * g + 2];
    o[3] = T[d][4 * g + 3];
    *(bf16x4*)(Vt + ((size_t)h * HD + d) * KVP + j) = o;
  }
}

// ---- flash attention: QBLK=128, reg-staged single LDS buffer, defer-max ----
__global__ __launch_bounds__(256, 3) void attn_split(const bf16* __restrict__ Qh,
                                                     const bf16* __restrict__ Kcat,
                                                     const bf16* __restrict__ Vtg,
                                                     float* __restrict__ Opart,
                                                     float* __restrict__ MLpart) {
  // XCD swizzle: 936 = 8*117 exactly
  int orig = blockIdx.x;
  int wgid = (orig & 7) * 117 + (orig >> 3);
  int qt = wgid % NQT;
  int rest = wgid / NQT;
  int h = rest % NH;
  int sp = rest / NH;
  int q0 = qt * QBLK;
  int c0 = sp * CHUNK;
  int cEnd = c0 + CHUNK < KVP ? c0 + CHUNK : KVP;
  int nt = (cEnd - c0) >> 6;

  int t = threadIdx.x, lane = t & 63, w = t >> 6;
  int g = lane >> 4, fr = lane & 15, s3 = fr & 7;

  __shared__ __align__(16) bf16 Klds[64 * 128];     // 16 KB, XOR-swizzled 16B blocks
  __shared__ __align__(16) bf16 Vlds[128 * 64];     // 16 KB
  __shared__ __align__(16) bf16 Plds[4][2][1024];   // 16 KB: per wave, per qset

  // Q fragments (B-operand), 2 qsets of 16 rows: q = q0 + w*32 + s*16 + fr
  bf16x8 qf[2][4];
#pragma unroll
  for (int s = 0; s < 2; ++s) {
    int qrow = q0 + w * 32 + s * 16 + fr;
    int qcl = qrow < SEQ ? qrow : SEQ - 1;
    const bf16* Qp = Qh + ((size_t)h * SEQ + qcl) * HD + g * 8;
#pragma unroll
    for (int fk = 0; fk < 4; ++fk) qf[s][fk] = *(const bf16x8*)(Qp + 32 * fk);
  }

  // staging addresses: linear global source, swizzled LDS dest
  int kgo[4], vgo[4], kwo[4], vwo[4];
#pragma unroll
  for (int p = 0; p < 4; ++p) {
    int m = (4 * w + p) * 64 + lane;
    int rK = m >> 4, cK = m & 15;
    kgo[p] = rK * HD + cK * 8;
    kwo[p] = rK * 256 + ((cK ^ (rK & 7)) * 16);
    int dV = m >> 3, cV = m & 7;
    vgo[p] = dV * KVP + cV * 8;
    vwo[p] = dV * 128 + ((cV ^ (dV & 7)) * 16);
  }

  // LDS read offsets (swizzled)
  int koffr[4], voffc[2], poffc[2], pwb[4];
#pragma unroll
  for (int fk = 0; fk < 4; ++fk) koffr[fk] = fr * 256 + (((g + 4 * fk) ^ s3) * 16);
#pragma unroll
  for (int c = 0; c < 2; ++c) {
    voffc[c] = fr * 128 + (((g + 4 * c) ^ s3) * 16);
    poffc[c] = fr * 128 + (((4 * c + g) ^ s3) * 16);
  }
#pragma unroll
  for (int fj = 0; fj < 4; ++fj)
    pwb[fj] = fr * 128 + (((2 * fj + (g >> 1)) ^ s3) * 16) + (g & 1) * 8;

  const bf16* Khp = Kcat + (size_t)h * KVP * HD;
  const bf16* Vhp = Vtg + (size_t)h * HD * KVP;

  int4 kreg[4], vreg[4];
#define GLOAD(j)                                         \
  {                                                      \
    const bf16* Kt = Khp + (size_t)(j)*HD;               \
    const bf16* Vp = Vhp + (j);                          \
    _Pragma("unroll") for (int p = 0; p < 4; ++p) {      \
      kreg[p] = *(const int4*)(Kt + kgo[p]);             \
      vreg[p] = *(const int4*)(Vp + vgo[p]);             \
    }                                                    \
  }

  f32x4 oacc[2][8] = {};
  float m_q[2] = {-1e38f, -1e38f};
  float l_q[2] = {0.f, 0.f};

  GLOAD(c0);
  for (int ti = 0; ti < nt; ++ti) {
    int j0 = c0 + ti * 64;
    // write staged regs (compiler waits vmcnt on kreg/vreg use)
#pragma unroll
    for (int p = 0; p < 4; ++p) {
      *(int4*)((char*)Klds + kwo[p]) = kreg[p];
      *(int4*)((char*)Vlds + vwo[p]) = vreg[p];
    }
    __syncthreads();  // tile visible (drains lgkm+vm)
    if (ti + 1 < nt) GLOAD(j0 + 64);  // issue next tile early; hides under compute

    // S^T = K Q^T : lane holds S[q=fr][k=16fj+4g+r] (log2 domain)
    f32x4 sacc[2][4] = {};
    __builtin_amdgcn_s_setprio(1);
#pragma unroll
    for (int fj = 0; fj < 4; ++fj)
#pragma unroll
      for (int fk = 0; fk < 4; ++fk) {
        bf16x8 kf = *(const bf16x8*)((const char*)Klds + fj * 4096 + koffr[fk]);
        sacc[0][fj] = __builtin_amdgcn_mfma_f32_16x16x32_bf16(kf, qf[0][fk], sacc[0][fj], 0, 0, 0);
        sacc[1][fj] = __builtin_amdgcn_mfma_f32_16x16x32_bf16(kf, qf[1][fk], sacc[1][fj], 0, 0, 0);
      }
    __builtin_amdgcn_s_setprio(0);

    if (j0 + 64 > KV) {
#pragma unroll
      for (int fj = 0; fj < 4; ++fj)
#pragma unroll
        for (int r = 0; r < 4; ++r)
          if (j0 + 16 * fj + 4 * g + r >= KV) {
            sacc[0][fj][r] = -1e38f;
            sacc[1][fj][r] = -1e38f;
          }
    }

    // tree max per qset
    float mx[2];
#pragma unroll
    for (int s = 0; s < 2; ++s) {
      f32x4 t4 = vmax4(vmax4(sacc[s][0], sacc[s][1]), vmax4(sacc[s][2], sacc[s][3]));
      float m0 = fmaxf(fmaxf(t4[0], t4[1]), fmaxf(t4[2], t4[3]));
      m0 = fmaxf(m0, __shfl_xor(m0, 16));
      mx[s] = fmaxf(m0, __shfl_xor(m0, 32));
    }
    // defer-max: rescale only when max grows by > 8 (log2 units)
    if (__any(fmaxf(mx[0] - m_q[0], mx[1] - m_q[1]) > 8.f)) {
#pragma unroll
      for (int s = 0; s < 2; ++s) {
        float mnew = fmaxf(m_q[s], mx[s]);
        float corr = exp2f(m_q[s] - mnew);
        m_q[s] = mnew;
        l_q[s] *= corr;
        float corr_r[4];
#pragma unroll
        for (int r = 0; r < 4; ++r) corr_r[r] = __shfl(corr, 4 * g + r);
#pragma unroll
        for (int fd = 0; fd < 8; ++fd)
#pragma unroll
          for (int r = 0; r < 4; ++r) oacc[s][fd][r] *= corr_r[r];
      }
    }
    // P = exp2(s - m), tree sum, write to per-(wave,qset) LDS
#pragma unroll
    for (int s = 0; s < 2; ++s) {
      f32x4 sum4 = {0.f, 0.f, 0.f, 0.f};
      bf16x4 pw[4];
#pragma unroll
      for (int fj = 0; fj < 4; ++fj) {
#pragma unroll
        for (int r = 0; r < 4; ++r) {
          float e = exp2f(sacc[s][fj][r] - m_q[s]);
          pw[fj][r] = (bf16)e;
          sum4[r] += e;
        }
      }
      float sum = (sum4[0] + sum4[1]) + (sum4[2] + sum4[3]);
      sum += __shfl_xor(sum, 16);
      sum += __shfl_xor(sum, 32);
      l_q[s] += sum;
      char* PB = (char*)&Plds[w][s][0];
#pragma unroll
      for (int fj = 0; fj < 4; ++fj) *(bf16x4*)(PB + pwb[fj]) = pw[fj];
    }

    bf16x8 pa[2][2];
#pragma unroll
    for (int s = 0; s < 2; ++s) {
      const char* PB = (const char*)&Plds[w][s][0];
      pa[s][0] = *(const bf16x8*)(PB + poffc[0]);
      pa[s][1] = *(const bf16x8*)(PB + poffc[1]);
    }

    __builtin_amdgcn_s_setprio(1);
#pragma unroll
    for (int fd = 0; fd < 8; ++fd) {
      bf16x8 v0 = *(const bf16x8*)((const char*)Vlds + fd * 2048 + voffc[0]);
      bf16x8 v1 = *(const bf16x8*)((const char*)Vlds + fd * 2048 + voffc[1]);
      oacc[0][fd] = __builtin_amdgcn_mfma_f32_16x16x32_bf16(pa[0][0], v0, oacc[0][fd], 0, 0, 0);
      oacc[0][fd] = __builtin_amdgcn_mfma_f32_16x16x32_bf16(pa[0][1], v1, oacc[0][fd], 0, 0, 0);
      oacc[1][fd] = __builtin_amdgcn_mfma_f32_16x16x32_bf16(pa[1][0], v0, oacc[1][fd], 0, 0, 0);
      oacc[1][fd] = __builtin_amdgcn_mfma_f32_16x16x32_bf16(pa[1][1], v1, oacc[1][fd], 0, 0, 0);
    }
    __builtin_amdgcn_s_setprio(0);

    __syncthreads();  // all reads done before next tile's ds_write
  }
#undef GLOAD

  // store unnormalized partials
  float* Oh = Opart + ((size_t)sp * NH + h) * SEQ * HD;
  float* MLh = MLpart + ((size_t)sp * NH + h) * SEQ * 2;
#pragma unroll
  for (int s = 0; s < 2; ++s) {
#pragma unroll
    for (int r = 0; r < 4; ++r) {
      int q = q0 + w * 32 + s * 16 + 4 * g + r;
      if (q >= SEQ) continue;
#pragma unroll
      for (int fd = 0; fd < 8; ++fd)
        Oh[(size_t)q * HD + fr + 16 * fd] = oacc[s][fd][r];
    }
  }
  if (lane < 16) {
#pragma unroll
    for (int s = 0; s < 2; ++s) {
      int q = q0 + w * 32 + s * 16 + lane;
      if (q < SEQ) {
        MLh[q * 2 + 0] = m_q[s];
        MLh[q * 2 + 1] = l_q[s];
      }
    }
  }
}

// ---------------- merge split partials (log2-domain m) ----------------
__global__ __launch_bounds__(256) void attn_merge(const float* __restrict__ Opart,
                                                  const float* __restrict__ MLpart,
                                                  bf16* __restrict__ Aout) {
  int idx = blockIdx.x * 2 + (threadIdx.x >> 7);
  if (idx >= NH * SEQ) return;
  int d = threadIdx.x & 127;
  int h = idx / SEQ, q = idx % SEQ;
  float m[NSPLIT];
  float M = -1e38f;
#pragma unroll
  for (int s = 0; s < NSPLIT; ++s) {
    m[s] = MLpart[(((size_t)s * NH + h) * SEQ + q) * 2];
    M = fmaxf(M, m[s]);
  }
  float L = 0.f, o = 0.f;
#pragma unroll
  for (int s = 0; s < NSPLIT; ++s) {
    float wgt = exp2f(m[s] - M);
    L += MLpart[(((size_t)s * NH + h) * SEQ + q) * 2 + 1] * wgt;
    o += Opart[((((size_t)s * NH + h) * SEQ + q)) * HD + d] * wgt;
  }
  Aout[(size_t)q * DIM + h * HD + d] = (bf16)(o / L);
}

// ---------------- host ----------------
extern "C" void kernel_launch(void* const* d_in, const int* in_sizes, int n_in,
                              void* d_out, int out_size, void* d_ws, size_t ws_size,
                              hipStream_t stream) {
  const float* x = (const float*)d_in[0];
  const float* Wq = (const float*)d_in[1];
  const float* bq = (const float*)d_in[2];
  const float* Wk = (const float*)d_in[3];
  const float* bk = (const float*)d_in[4];
  const float* Wv = (const float*)d_in[5];
  const float* bv = (const float*)d_in[6];
  const float* Wo = (const float*)d_in[7];
  const float* bo = (const float*)d_in[8];
  const float* nqw = (const float*)d_in[9];
  const float* nkw = (const float*)d_in[10];
  const float* cache_k = (const float*)d_in[11];
  const float* cache_v = (const float*)d_in[12];
  const float* fcos = (const float*)d_in[13];
  const float* fsin = (const float*)d_in[14];
  float* out = (float*)d_out;

  char* ws = (char*)d_ws;
  size_t off = 0;
  auto alloc = [&](size_t bytes) {
    char* p = ws + off;
    off += (bytes + 255) & ~(size_t)255;
    return p;
  };
  const int XN = SEQ * DIM;       // 2,396,160
  const int WN = DIM * DIM;       // 2,359,296
  bf16* xb = (bf16*)alloc((size_t)XN * 2);
  bf16* Wqb = (bf16*)alloc((size_t)WN * 2);
  bf16* Wkb = (bf16*)alloc((size_t)WN * 2);
  bf16* Wvb = (bf16*)alloc((size_t)WN * 2);
  bf16* Wob = (bf16*)alloc((size_t)WN * 2);
  bf16* QhB = (bf16*)alloc((size_t)NH * SEQ * HD * 2);
  bf16* Kcat = (bf16*)alloc((size_t)NH * KVP * HD * 2);
  bf16* Vt = (bf16*)alloc((size_t)NH * HD * KVP * 2);
  bf16* Aout = (bf16*)alloc((size_t)XN * 2);
  float* MLpart = (float*)alloc((size_t)NSPLIT * NH * SEQ * 2 * 4);
  // Opart (written by attn_split) overlays qraw/kraw/vraw (dead after build_vt)
  float* Opart = (float*)alloc((size_t)NSPLIT * NH * SEQ * HD * 4);
  float* qraw = Opart;
  float* kraw = qraw + XN;
  float* vraw = kraw + XN;

  castk<<<(XN + 2047) / 2048, 256, 0, stream>>>(x, xb, XN);
  castk<<<(WN + 2047) / 2048, 256, 0, stream>>>(Wq, Wqb, WN);
  castk<<<(WN + 2047) / 2048, 256, 0, stream>>>(Wk, Wkb, WN);
  castk<<<(WN + 2047) / 2048, 256, 0, stream>>>(Wv, Wvb, WN);
  castk<<<(WN + 2047) / 2048, 256, 0, stream>>>(Wo, Wob, WN);

  GemmBatch gqkv;
  gqkv.B[0] = Wqb; gqkv.B[1] = Wkb; gqkv.B[2] = Wvb;
  gqkv.bias[0] = bq; gqkv.bias[1] = bk; gqkv.bias[2] = bv;
  gqkv.C[0] = qraw; gqkv.C[1] = kraw; gqkv.C[2] = vraw;
  gemm_bt<<<dim3(13, 12, 3), 256, 0, stream>>>(xb, gqkv, SEQ);

  norm_rope<<<SEQ, 256, 0, stream>>>(qraw, kraw, nqw, nkw, fcos, fsin, QhB, Kcat);
  build_kcat<<<NEWBASE, 256, 0, stream>>>(cache_k, Kcat);
  build_vt<<<dim3(147, NH), 256, 0, stream>>>(cache_v, vraw, Vt);

  attn_split<<<dim3(NQT * NH * NSPLIT), 256, 0, stream>>>(QhB, Kcat, Vt, Opart, MLpart);
  attn_merge<<<(NH * SEQ + 1) / 2, 256, 0, stream>>>(Opart, MLpart, Aout);

  GemmBatch gout;
  gout.B[0] = Wob; gout.B[1] = Wob; gout.B[2] = Wob;
  gout.bias[0] = bo; gout.bias[1] = bo; gout.bias[2] = bo;
  gout.C[0] = out; gout.C[1] = out; gout.C[2] = out;
  gemm_bt<<<dim3(13, 12, 1), 256, 0, stream>>>(Aout, gout, SEQ);
}

// Round 7
// 304.564 us; speedup vs baseline: 1.8366x; 1.8366x over previous
//
#include <hip/hip_runtime.h>
#include <hip/hip_bf16.h>

typedef __bf16 bf16;
typedef __bf16 bf16x2 __attribute__((ext_vector_type(2)));
typedef __bf16 bf16x4 __attribute__((ext_vector_type(4)));
typedef __bf16 bf16x8 __attribute__((ext_vector_type(8)));
typedef float f32x4 __attribute__((ext_vector_type(4)));

#define DIM 1536
#define NH 12
#define HD 128
#define SEQ 1560
#define KV 9360
#define KVP 9408      // padded to 147*64 so staging never needs clamps
#define SINK 1560
#define NEWBASE 7800  // k_cat rows [7800,9360) are the new tokens
// logits computed in log2 domain: Q pre-scaled by HD^-0.5 * log2(e)
#define QSCALE_L2E (0.08838834764831845f * 1.4426950408889634f)
#define NSPLIT 3
#define CHUNK 3136    // 49 tiles; 3*3136 = 9408 = KVP exactly
#define NT 49
#define QBLK 128
#define NQT 13        // ceil(1560/128)

__device__ __forceinline__ void gl_lds16(const void* g, void* l) {
  __builtin_amdgcn_global_load_lds(
      (const __attribute__((address_space(1))) unsigned int*)g,
      (__attribute__((address_space(3))) unsigned int*)l, 16, 0, 0);
}

__device__ __forceinline__ f32x4 vmax4(f32x4 a, f32x4 b) {
  f32x4 r;
  r[0] = fmaxf(a[0], b[0]); r[1] = fmaxf(a[1], b[1]);
  r[2] = fmaxf(a[2], b[2]); r[3] = fmaxf(a[3], b[3]);
  return r;
}

// ---------------- cast f32 -> bf16 (single) ----------------
__global__ __launch_bounds__(256) void castk(const float* __restrict__ src,
                                             bf16* __restrict__ dst, int n) {
  int i = (blockIdx.x * 256 + threadIdx.x) * 8;
  if (i < n) {
    float4 a = *(const float4*)(src + i);
    float4 b = *(const float4*)(src + i + 4);
    bf16x8 o;
    o[0] = (bf16)a.x; o[1] = (bf16)a.y; o[2] = (bf16)a.z; o[3] = (bf16)a.w;
    o[4] = (bf16)b.x; o[5] = (bf16)b.y; o[6] = (bf16)b.z; o[7] = (bf16)b.w;
    *(bf16x8*)(dst + i) = o;
  }
}

// ---------------- fused cast of the 4 weight matrices ----------------
struct CastBatch {
  const float* src[4];
  bf16* dst[4];
};
__global__ __launch_bounds__(256) void castw(CastBatch cb, int n) {
  const float* src = cb.src[blockIdx.y];
  bf16* dst = cb.dst[blockIdx.y];
  int i = (blockIdx.x * 256 + threadIdx.x) * 8;
  if (i < n) {
    float4 a = *(const float4*)(src + i);
    float4 b = *(const float4*)(src + i + 4);
    bf16x8 o;
    o[0] = (bf16)a.x; o[1] = (bf16)a.y; o[2] = (bf16)a.z; o[3] = (bf16)a.w;
    o[4] = (bf16)b.x; o[5] = (bf16)b.y; o[6] = (bf16)b.z; o[7] = (bf16)b.w;
    *(bf16x8*)(dst + i) = o;
  }
}

// ---------------- GEMM: C[M,N] = A[M,K] * B[N,K]^T + bias, f32 out ----------------
struct GemmBatch {
  const bf16* B[3];
  const float* bias[3];
  float* C[3];
};

#define BM 128
#define BN 128
#define BK 32

__global__ __launch_bounds__(256, 2) void gemm_bt(const bf16* __restrict__ A,
                                                  GemmBatch gb, int M) {
  const bf16* Bw = gb.B[blockIdx.z];
  const float* bias = gb.bias[blockIdx.z];
  float* C = gb.C[blockIdx.z];
  int bm = blockIdx.x * BM;
  int bn = blockIdx.y * BN;

  __shared__ bf16 Alds[2][BM][BK];
  __shared__ bf16 Blds[2][BN][BK];

  int t = threadIdx.x;
  int lane = t & 63;
  int wave = t >> 6;
  int wr = wave >> 1, wc = wave & 1;
  int fr = lane & 15;
  int fo = (lane >> 4) * 8;

  f32x4 acc[4][4] = {};

  const int NK = DIM / BK;  // 48
  int colA = (lane & 3) * 8;
  int lrow = lane >> 2;

#define STAGEG(buf, k0)                                                     \
  {                                                                         \
    _Pragma("unroll") for (int p = 0; p < 2; ++p) {                         \
      int rbase = wave * 16 + p * 64;                                       \
      int ga = bm + rbase + lrow;                                           \
      if (ga > M - 1) ga = M - 1;                                           \
      gl_lds16(A + (size_t)ga * DIM + (k0) + colA, &Alds[buf][rbase][0]);   \
      int gbv = bn + rbase + lrow;                                          \
      gl_lds16(Bw + (size_t)gbv * DIM + (k0) + colA, &Blds[buf][rbase][0]); \
    }                                                                       \
  }

  STAGEG(0, 0);
  int cur = 0;
  for (int ks = 0; ks < NK; ++ks) {
    __syncthreads();  // drains vmcnt -> buf[cur] ready
    if (ks + 1 < NK) STAGEG(cur ^ 1, (ks + 1) * BK);
    bf16x8 af[4], bfv[4];
#pragma unroll
    for (int i = 0; i < 4; ++i)
      af[i] = *(const bf16x8*)&Alds[cur][wr * 64 + i * 16 + fr][fo];
#pragma unroll
    for (int j = 0; j < 4; ++j)
      bfv[j] = *(const bf16x8*)&Blds[cur][wc * 64 + j * 16 + fr][fo];
#pragma unroll
    for (int i = 0; i < 4; ++i)
#pragma unroll
      for (int j = 0; j < 4; ++j)
        acc[i][j] = __builtin_amdgcn_mfma_f32_16x16x32_bf16(af[i], bfv[j],
                                                            acc[i][j], 0, 0, 0);
    cur ^= 1;
  }
#undef STAGEG

  int g4 = (lane >> 4) * 4;
#pragma unroll
  for (int i = 0; i < 4; ++i) {
    int mbase = bm + wr * 64 + i * 16 + g4;
#pragma unroll
    for (int j = 0; j < 4; ++j) {
      int col = bn + wc * 64 + j * 16 + fr;
      float bv = bias[col];
#pragma unroll
      for (int r = 0; r < 4; ++r) {
        int m = mbase + r;
        if (m < M) C[(size_t)m * DIM + col] = acc[i][j][r] + bv;
      }
    }
  }
}

// ---------------- RMSNorm + RoPE for q,k ----------------
__global__ __launch_bounds__(256) void norm_rope(
    const float* __restrict__ qraw, const float* __restrict__ kraw,
    const float* __restrict__ nqw, const float* __restrict__ nkw,
    const float* __restrict__ fcos, const float* __restrict__ fsin,
    bf16* __restrict__ Qh, bf16* __restrict__ Kcat) {
  int tok = blockIdx.x;
  int tid = threadIdx.x;
  const float* qr = qraw + (size_t)tok * DIM;
  const float* kr = kraw + (size_t)tok * DIM;
  float sq = 0.f, sk = 0.f;
  for (int c = tid; c < DIM; c += 256) {
    float a = qr[c];
    sq += a * a;
    float b = kr[c];
    sk += b * b;
  }
#pragma unroll
  for (int off = 32; off; off >>= 1) {
    sq += __shfl_down(sq, off);
    sk += __shfl_down(sk, off);
  }
  __shared__ float red[2][4];
  int w = tid >> 6;
  if ((tid & 63) == 0) {
    red[0][w] = sq;
    red[1][w] = sk;
  }
  __syncthreads();
  sq = red[0][0] + red[0][1] + red[0][2] + red[0][3];
  sk = red[1][0] + red[1][1] + red[1][2] + red[1][3];
  float rsq = rsqrtf(sq * (1.0f / DIM) + 1e-6f);
  float rsk = rsqrtf(sk * (1.0f / DIM) + 1e-6f);

  int hrow = tok / 52, wrow = tok % 52;
  for (int p = tid; p < NH * 64; p += 256) {
    int n = p >> 6, i = p & 63;
    int trow = (i < 22) ? 6 : (i < 43 ? hrow : wrow);
    float cs = fcos[trow * 64 + i];
    float sn = fsin[trow * 64 + i];
    int c = n * HD + 2 * i;
    float xr = qr[c] * rsq * nqw[c];
    float xi = qr[c + 1] * rsq * nqw[c + 1];
    bf16x2 qo;
    qo[0] = (bf16)((xr * cs - xi * sn) * QSCALE_L2E);
    qo[1] = (bf16)((xr * sn + xi * cs) * QSCALE_L2E);
    *(bf16x2*)(Qh + ((size_t)n * SEQ + tok) * HD + 2 * i) = qo;
    float yr = kr[c] * rsk * nkw[c];
    float yi = kr[c + 1] * rsk * nkw[c + 1];
    bf16x2 ko;
    ko[0] = (bf16)(yr * cs - yi * sn);
    ko[1] = (bf16)(yr * sn + yi * cs);
    *(bf16x2*)(Kcat + ((size_t)n * KVP + NEWBASE + tok) * HD + 2 * i) = ko;
  }
}

// ---------------- gather cache_k rows into K_cat ----------------
__global__ __launch_bounds__(256) void build_kcat(const float* __restrict__ cache_k,
                                                  bf16* __restrict__ Kcat) {
  int j = blockIdx.x;  // 0..7799
  int src = j < SINK ? j : j + SINK;
  const float* sp = cache_k + (size_t)src * DIM;
  for (int c4 = threadIdx.x; c4 < DIM / 4; c4 += 256) {
    float4 v = *(const float4*)(sp + c4 * 4);
    int c = c4 * 4;
    int n = c >> 7, d = c & 127;
    bf16x4 o;
    o[0] = (bf16)v.x; o[1] = (bf16)v.y; o[2] = (bf16)v.z; o[3] = (bf16)v.w;
    *(bf16x4*)(Kcat + ((size_t)n * KVP + j) * HD + d) = o;
  }
}

// ---------------- build transposed V: Vt[h][d][j] ----------------
__global__ __launch_bounds__(256) void build_vt(const float* __restrict__ cache_v,
                                                const float* __restrict__ vraw,
                                                bf16* __restrict__ Vt) {
  int h = blockIdx.y;
  int j0 = blockIdx.x * 64;
  __shared__ bf16 T[128][72];
  int tid = threadIdx.x;
  for (int idx = tid; idx < 64 * 32; idx += 256) {
    int jl = idx >> 5, s = idx & 31;
    int j = j0 + jl;
    if (j >= KV) continue;
    const float* sp;
    if (j < NEWBASE) {
      int srcj = j < SINK ? j : j + SINK;
      sp = cache_v + (size_t)srcj * DIM + h * HD;
    } else {
      sp = vraw + (size_t)(j - NEWBASE) * DIM + h * HD;
    }
    float4 v = *(const float4*)(sp + s * 4);
    T[s * 4 + 0][jl] = (bf16)v.x;
    T[s * 4 + 1][jl] = (bf16)v.y;
    T[s * 4 + 2][jl] = (bf16)v.z;
    T[s * 4 + 3][jl] = (bf16)v.w;
  }
  __syncthreads();
  for (int idx = tid; idx < 128 * 16; idx += 256) {
    int d = idx >> 4, g = idx & 15;
    int j = j0 + g * 4;
    if (j + 4 > KV) continue;
    bf16x4 o;
    o[0] = T[d][4 * g];
    o[1] = T[d][4 * g + 1];
    o[2] = T[d][4 * g + 2];
    o[3] = T[d][4 * g + 3];
    *(bf16x4*)(Vt + ((size_t)h * HD + d) * KVP + j) = o;
  }
}

// ---- flash attention: QBLK=128, dbuf gl_lds16 staging, exp2 softmax, defer-max ----
__global__ __launch_bounds__(256, 2) void attn_split(const bf16* __restrict__ Qh,
                                                     const bf16* __restrict__ Kcat,
                                                     const bf16* __restrict__ Vtg,
                                                     float* __restrict__ Opart,
                                                     float* __restrict__ MLpart) {
  // bijective XCD swizzle (m204): NB = 13*12*3 = 468, q=58, r=4
  int orig = blockIdx.x;
  int xcd = orig & 7, jj = orig >> 3;
  int wgid = (xcd < 4 ? xcd * 59 : 236 + (xcd - 4) * 58) + jj;
  int qt = wgid % NQT;
  int h = (wgid / NQT) % NH;
  int sp = wgid / (NQT * NH);
  int q0 = qt * QBLK;
  int c0 = sp * CHUNK;

  int t = threadIdx.x, lane = t & 63, w = t >> 6;
  int g = lane >> 4, fr = lane & 15, s3 = fr & 7;

  __shared__ bf16 Klds[2][64][128];     // 2 x 16 KB, XOR-swizzled 16B blocks
  __shared__ bf16 Vlds[2][128][64];     // 2 x 16 KB
  __shared__ bf16 Plds[4][2][16][64];   // 16 KB: per wave, per qset

  // Q fragments (B-operand), 2 qsets of 16 rows each: q = q0 + w*32 + s*16 + fr
  bf16x8 qf[2][4];
#pragma unroll
  for (int s = 0; s < 2; ++s) {
    int qrow = q0 + w * 32 + s * 16 + fr;
    int qcl = qrow < SEQ ? qrow : SEQ - 1;
    const bf16* Qp = Qh + ((size_t)h * SEQ + qcl) * HD + g * 8;
#pragma unroll
    for (int fk = 0; fk < 4; ++fk) qf[s][fk] = *(const bf16x8*)(Qp + 32 * fk);
  }

  // staging source offsets (pre-swizzled global, linear LDS dest)
  int kadd[4], vadd[4];
#pragma unroll
  for (int p = 0; p < 4; ++p) {
    int m = (4 * w + p) * 64 + lane;
    int rK = m >> 4, cK = m & 15;
    kadd[p] = rK * HD + (cK ^ (rK & 7)) * 8;
    int dV = m >> 3, cV = m & 7;
    vadd[p] = dV * KVP + (cV ^ (dV & 7)) * 8;
  }
  char* Kbase = (char*)&Klds[0][0][0];
  char* Vbase = (char*)&Vlds[0][0][0];

  // LDS read/write byte offsets (swizzled)
  int koffr[4], voffc[2], poffc[2], pwb[4];
#pragma unroll
  for (int fk = 0; fk < 4; ++fk) koffr[fk] = fr * 256 + (((g + 4 * fk) ^ s3) * 16);
#pragma unroll
  for (int c = 0; c < 2; ++c) {
    voffc[c] = fr * 128 + (((g + 4 * c) ^ s3) * 16);
    poffc[c] = fr * 128 + (((4 * c + g) ^ s3) * 16);
  }
#pragma unroll
  for (int fj = 0; fj < 4; ++fj)
    pwb[fj] = fr * 128 + (((2 * fj + (g >> 1)) ^ s3) * 16) + (g & 1) * 8;
  char* PldsB0 = (char*)&Plds[w][0][0][0];
  char* PldsB1 = (char*)&Plds[w][1][0][0];

  const bf16* Khp = Kcat + (size_t)h * KVP * HD;
  const bf16* Vhp = Vtg + (size_t)h * HD * KVP;

  f32x4 oacc[2][8] = {};
  float m_q[2] = {-1e38f, -1e38f};
  float l_q[2] = {0.f, 0.f};

#define STAGE(buf, j0)                                                   \
  {                                                                      \
    const bf16* Ks = Khp + (size_t)(j0)*HD;                              \
    const bf16* Vs = Vhp + (j0);                                         \
    _Pragma("unroll") for (int p = 0; p < 4; ++p)                        \
        gl_lds16(Ks + kadd[p], Kbase + (buf)*16384 + w * 4096 + p * 1024); \
    _Pragma("unroll") for (int p = 0; p < 4; ++p)                        \
        gl_lds16(Vs + vadd[p], Vbase + (buf)*16384 + w * 4096 + p * 1024); \
  }

  STAGE(0, c0);
  __syncthreads();  // drain vmcnt -> buf0 ready
  int cur = 0;

  for (int ti = 0; ti < NT; ++ti) {
    int j0 = c0 + ti * 64;
    if (ti + 1 < NT) STAGE(cur ^ 1, j0 + 64);  // prefetch overlaps compute

    const char* Kc = Kbase + cur * 16384;
    const char* Vc = Vbase + cur * 16384;

    // S^T = K Q^T : lane holds S[q=fr][k=16fj+4g+r] (log2 domain)
    f32x4 sacc[2][4] = {};
    __builtin_amdgcn_s_setprio(1);
#pragma unroll
    for (int fj = 0; fj < 4; ++fj)
#pragma unroll
      for (int fk = 0; fk < 4; ++fk) {
        bf16x8 kf = *(const bf16x8*)(Kc + fj * 4096 + koffr[fk]);
        sacc[0][fj] = __builtin_amdgcn_mfma_f32_16x16x32_bf16(kf, qf[0][fk], sacc[0][fj], 0, 0, 0);
        sacc[1][fj] = __builtin_amdgcn_mfma_f32_16x16x32_bf16(kf, qf[1][fk], sacc[1][fj], 0, 0, 0);
      }
    __builtin_amdgcn_s_setprio(0);

    if (j0 + 64 > KV) {
#pragma unroll
      for (int fj = 0; fj < 4; ++fj)
#pragma unroll
        for (int r = 0; r < 4; ++r)
          if (j0 + 16 * fj + 4 * g + r >= KV) {
            sacc[0][fj][r] = -1e38f;
            sacc[1][fj][r] = -1e38f;
          }
    }

    // tree max per qset
    float mx[2];
#pragma unroll
    for (int s = 0; s < 2; ++s) {
      f32x4 t4 = vmax4(vmax4(sacc[s][0], sacc[s][1]), vmax4(sacc[s][2], sacc[s][3]));
      float m0 = fmaxf(fmaxf(t4[0], t4[1]), fmaxf(t4[2], t4[3]));
      m0 = fmaxf(m0, __shfl_xor(m0, 16));
      mx[s] = fmaxf(m0, __shfl_xor(m0, 32));
    }
    // defer-max: rescale only when max grows by > 8 (log2 units)
    if (__any(fmaxf(mx[0] - m_q[0], mx[1] - m_q[1]) > 8.f)) {
#pragma unroll
      for (int s = 0; s < 2; ++s) {
        float mnew = fmaxf(m_q[s], mx[s]);
        float corr = exp2f(m_q[s] - mnew);
        m_q[s] = mnew;
        l_q[s] *= corr;
        float corr_r[4];
#pragma unroll
        for (int r = 0; r < 4; ++r) corr_r[r] = __shfl(corr, 4 * g + r);
#pragma unroll
        for (int fd = 0; fd < 8; ++fd)
#pragma unroll
          for (int r = 0; r < 4; ++r) oacc[s][fd][r] *= corr_r[r];
      }
    }

    // P = exp2(s - m), tree sum, write to per-(wave,qset) LDS
#pragma unroll
    for (int s = 0; s < 2; ++s) {
      f32x4 sum4 = {0.f, 0.f, 0.f, 0.f};
      bf16x4 pw[4];
#pragma unroll
      for (int fj = 0; fj < 4; ++fj) {
#pragma unroll
        for (int r = 0; r < 4; ++r) {
          float e = exp2f(sacc[s][fj][r] - m_q[s]);
          pw[fj][r] = (bf16)e;
          sum4[r] += e;
        }
      }
      float sum = (sum4[0] + sum4[1]) + (sum4[2] + sum4[3]);
      sum += __shfl_xor(sum, 16);
      sum += __shfl_xor(sum, 32);
      l_q[s] += sum;
      char* PB = s ? PldsB1 : PldsB0;
#pragma unroll
      for (int fj = 0; fj < 4; ++fj) *(bf16x4*)(PB + pwb[fj]) = pw[fj];
    }

    bf16x8 pa[2][2];
#pragma unroll
    for (int c = 0; c < 2; ++c) {
      pa[0][c] = *(const bf16x8*)(PldsB0 + poffc[c]);
      pa[1][c] = *(const bf16x8*)(PldsB1 + poffc[c]);
    }
    __builtin_amdgcn_s_setprio(1);
#pragma unroll
    for (int fd = 0; fd < 8; ++fd) {
      bf16x8 v0 = *(const bf16x8*)(Vc + fd * 2048 + voffc[0]);
      bf16x8 v1 = *(const bf16x8*)(Vc + fd * 2048 + voffc[1]);
      oacc[0][fd] = __builtin_amdgcn_mfma_f32_16x16x32_bf16(pa[0][0], v0, oacc[0][fd], 0, 0, 0);
      oacc[0][fd] = __builtin_amdgcn_mfma_f32_16x16x32_bf16(pa[0][1], v1, oacc[0][fd], 0, 0, 0);
      oacc[1][fd] = __builtin_amdgcn_mfma_f32_16x16x32_bf16(pa[1][0], v0, oacc[1][fd], 0, 0, 0);
      oacc[1][fd] = __builtin_amdgcn_mfma_f32_16x16x32_bf16(pa[1][1], v1, oacc[1][fd], 0, 0, 0);
    }
    __builtin_amdgcn_s_setprio(0);

    __syncthreads();  // drains next-tile loads + WAR on cur
    cur ^= 1;
  }
#undef STAGE

  // store unnormalized partials
  float* Oh = Opart + ((size_t)sp * NH + h) * SEQ * HD;
  float* MLh = MLpart + ((size_t)sp * NH + h) * SEQ * 2;
#pragma unroll
  for (int s = 0; s < 2; ++s) {
#pragma unroll
    for (int r = 0; r < 4; ++r) {
      int q = q0 + w * 32 + s * 16 + 4 * g + r;
      if (q >= SEQ) continue;
#pragma unroll
      for (int fd = 0; fd < 8; ++fd)
        Oh[(size_t)q * HD + fr + 16 * fd] = oacc[s][fd][r];
    }
  }
  if (lane < 16) {
#pragma unroll
    for (int s = 0; s < 2; ++s) {
      int q = q0 + w * 32 + s * 16 + lane;
      if (q < SEQ) {
        MLh[q * 2 + 0] = m_q[s];
        MLh[q * 2 + 1] = l_q[s];
      }
    }
  }
}

// ---------------- merge split partials (log2-domain m) ----------------
__global__ __launch_bounds__(256) void attn_merge(const float* __restrict__ Opart,
                                                  const float* __restrict__ MLpart,
                                                  bf16* __restrict__ Aout) {
  int idx = blockIdx.x * 2 + (threadIdx.x >> 7);
  if (idx >= NH * SEQ) return;
  int d = threadIdx.x & 127;
  int h = idx / SEQ, q = idx % SEQ;
  float m[NSPLIT];
  float M = -1e38f;
#pragma unroll
  for (int s = 0; s < NSPLIT; ++s) {
    m[s] = MLpart[(((size_t)s * NH + h) * SEQ + q) * 2];
    M = fmaxf(M, m[s]);
  }
  float L = 0.f, o = 0.f;
#pragma unroll
  for (int s = 0; s < NSPLIT; ++s) {
    float wgt = exp2f(m[s] - M);
    L += MLpart[(((size_t)s * NH + h) * SEQ + q) * 2 + 1] * wgt;
    o += Opart[((((size_t)s * NH + h) * SEQ + q)) * HD + d] * wgt;
  }
  Aout[(size_t)q * DIM + h * HD + d] = (bf16)(o / L);
}

// ---------------- host ----------------
extern "C" void kernel_launch(void* const* d_in, const int* in_sizes, int n_in,
                              void* d_out, int out_size, void* d_ws, size_t ws_size,
                              hipStream_t stream) {
  const float* x = (const float*)d_in[0];
  const float* Wq = (const float*)d_in[1];
  const float* bq = (const float*)d_in[2];
  const float* Wk = (const float*)d_in[3];
  const float* bk = (const float*)d_in[4];
  const float* Wv = (const float*)d_in[5];
  const float* bv = (const float*)d_in[6];
  const float* Wo = (const float*)d_in[7];
  const float* bo = (const float*)d_in[8];
  const float* nqw = (const float*)d_in[9];
  const float* nkw = (const float*)d_in[10];
  const float* cache_k = (const float*)d_in[11];
  const float* cache_v = (const float*)d_in[12];
  const float* fcos = (const float*)d_in[13];
  const float* fsin = (const float*)d_in[14];
  float* out = (float*)d_out;

  char* ws = (char*)d_ws;
  size_t off = 0;
  auto alloc = [&](size_t bytes) {
    char* p = ws + off;
    off += (bytes + 255) & ~(size_t)255;
    return p;
  };
  const int XN = SEQ * DIM;       // 2,396,160
  const int WN = DIM * DIM;       // 2,359,296
  bf16* xb = (bf16*)alloc((size_t)XN * 2);
  bf16* Wqb = (bf16*)alloc((size_t)WN * 2);
  bf16* Wkb = (bf16*)alloc((size_t)WN * 2);
  bf16* Wvb = (bf16*)alloc((size_t)WN * 2);
  bf16* Wob = (bf16*)alloc((size_t)WN * 2);
  bf16* QhB = (bf16*)alloc((size_t)NH * SEQ * HD * 2);
  bf16* Kcat = (bf16*)alloc((size_t)NH * KVP * HD * 2);
  bf16* Vt = (bf16*)alloc((size_t)NH * HD * KVP * 2);
  bf16* Aout = (bf16*)alloc((size_t)XN * 2);
  float* MLpart = (float*)alloc((size_t)NSPLIT * NH * SEQ * 2 * 4);
  // Opart (written by attn_split) overlays qraw/kraw/vraw (dead after build_vt);
  // NSPLIT*NH*SEQ*HD == 3*XN exactly.
  float* Opart = (float*)alloc((size_t)NSPLIT * NH * SEQ * HD * 4);
  float* qraw = Opart;
  float* kraw = qraw + XN;
  float* vraw = kraw + XN;

  castk<<<(XN + 2047) / 2048, 256, 0, stream>>>(x, xb, XN);
  CastBatch cb;
  cb.src[0] = Wq; cb.src[1] = Wk; cb.src[2] = Wv; cb.src[3] = Wo;
  cb.dst[0] = Wqb; cb.dst[1] = Wkb; cb.dst[2] = Wvb; cb.dst[3] = Wob;
  castw<<<dim3((WN + 2047) / 2048, 4), 256, 0, stream>>>(cb, WN);

  GemmBatch gqkv;
  gqkv.B[0] = Wqb; gqkv.B[1] = Wkb; gqkv.B[2] = Wvb;
  gqkv.bias[0] = bq; gqkv.bias[1] = bk; gqkv.bias[2] = bv;
  gqkv.C[0] = qraw; gqkv.C[1] = kraw; gqkv.C[2] = vraw;
  gemm_bt<<<dim3(13, 12, 3), 256, 0, stream>>>(xb, gqkv, SEQ);

  norm_rope<<<SEQ, 256, 0, stream>>>(qraw, kraw, nqw, nkw, fcos, fsin, QhB, Kcat);
  build_kcat<<<NEWBASE, 256, 0, stream>>>(cache_k, Kcat);
  build_vt<<<dim3(147, NH), 256, 0, stream>>>(cache_v, vraw, Vt);

  attn_split<<<dim3(NQT * NH * NSPLIT), 256, 0, stream>>>(QhB, Kcat, Vt, Opart, MLpart);
  attn_merge<<<(NH * SEQ + 1) / 2, 256, 0, stream>>>(Opart, MLpart, Aout);

  GemmBatch gout;
  gout.B[0] = Wob; gout.B[1] = Wob; gout.B[2] = Wob;
  gout.bias[0] = bo; gout.bias[1] = bo; gout.bias[2] = bo;
  gout.C[0] = out; gout.C[1] = out; gout.C[2] = out;
  gemm_bt<<<dim3(13, 12, 1), 256, 0, stream>>>(Aout, gout, SEQ);
}